// Round 3
// baseline (43.146 us; speedup 1.0000x reference)
//
#include <hip/hip_runtime.h>
#include <cstdint>

// CharEmb: per word (B*S=16384): gather 32 char embeddings (E=64) -> x[64][32]
// (raw view of the [32 chars][64] buffer), conv1d(F=128,K=3,valid,T=30), bias,
// max over t. Output float32 [16384][128].
//
// MFMA formulation (32x32x16 bf16), M=t, N=f (VERIFIED, absmax 0.031):
//   D[t][f] = sum_kk sum_e xT[t+kk][e] * W[f][e][kk]
// - xT[c][e] staged in LDS bf16, row stride 72 elems (144 B, 16B-aligned).
// - conv shift t+kk = pure LDS address offset on the A-fragment read.
// - A frag: A[m=lane&31][k=(lane>>5)*8+j]; B frag: B[k][n=lane&31] (pre-packed).
// - C/D: col=lane&31, row=(reg&3)+8*(reg>>2)+4*(lane>>5); t=30,31 masked.
//
// Round 5: SINGLE KERNEL. Rounds 2-4 proved the inner loop is not the
// bottleneck (3 orthogonal structural changes, all neutral): attributable
// kernel work sums to <10 us of the 35. The invariant was the 2-launch
// structure (prep_pack_w -> d_ws -> charcnn_mfma serialization). Now each
// block packs its own B fragments straight from conv_w [128][64][3] f32:
// per thread, per (nt,ks): 6 aligned float4 loads = the contiguous 24-float
// patch w[f][e0..e0+7][0..2], repacked in-register (frag[kk][j]=vf[j*3+kk]).
// conv_w = 98 KB -> L2-resident; latency hides under the cid/emb prologue.
// No workspace, no prep kernel, no inter-kernel bubble.

typedef __bf16 bf16x8 __attribute__((ext_vector_type(8)));
typedef float  f32x16 __attribute__((ext_vector_type(16)));

#define GW   2    // words staged per phase
#define NGRP 8    // phases per block; 16 words/block, 1024 blocks
#define NW   16   // words per block
#define ROWS 34
#define RST  72   // row stride in bf16 elems (36 dwords)

__global__ __launch_bounds__(256, 2)
void charcnn_mfma(const int* __restrict__ cid, const float* __restrict__ emb,
                  const float* __restrict__ bias, const float* __restrict__ wraw,
                  float* __restrict__ out) {
  // 8 word-buffers (ring), 34 rows x 72 bf16 = 4896 B each = 39168 B.
  __shared__ __align__(16) __bf16 xT[8][ROWS * RST];

  const int tid  = threadIdx.x;
  const int lane = tid & 63;
  const int wv   = tid >> 6;
  const int np   = wv & 1;    // f-tile pair: f in [np*64, np*64+64)
  const int ws   = wv >> 1;   // word parity this wave computes

  // staging map: thread -> (char slot a, float4 pair p)
  const int a  = tid >> 3;            // 0..31 (char within word)
  const int p  = tid & 7;             // 0..7  (float4 index)
  const int d0 = p * 4;               // row base (c = d0..d0+3)
  const int bw = blockIdx.x * NW;

  // cid loads first: longest-latency (HBM) chain, overlaps weight packing
  int chw[NW];
#pragma unroll
  for (int w = 0; w < NW; ++w) chw[w] = cid[(bw + w) * 32 + a];

  // pack B fragments (weights) for TWO f-tiles directly from conv_w.
  // bfrag[nt][kk*4+ks][j] = w[f=(np*2+nt)*32+(lane&31)][e=ks*16+(lane>>5)*8+j][kk]
  bf16x8 bfrag[2][12];
#pragma unroll
  for (int nt = 0; nt < 2; ++nt) {
    const int f = (np * 2 + nt) * 32 + (lane & 31);
#pragma unroll
    for (int ks = 0; ks < 4; ++ks) {
      const int e0 = ks * 16 + (lane >> 5) * 8;
      const float4* src = (const float4*)(wraw + f * 192 + e0 * 3);
      float4 v[6];
#pragma unroll
      for (int q = 0; q < 6; ++q) v[q] = src[q];
      const float* vf = (const float*)v;   // vf[j*3 + kk]
#pragma unroll
      for (int kk = 0; kk < 3; ++kk) {
        bf16x8 fr;
#pragma unroll
        for (int j = 0; j < 8; ++j) fr[j] = (__bf16)vf[j * 3 + kk];
        bfrag[nt][kk * 4 + ks] = fr;
      }
    }
  }

  const float vb0 = bias[(np * 2 + 0) * 32 + (lane & 31)];
  const float vb1 = bias[(np * 2 + 1) * 32 + (lane & 31)];

  // ping-pong in-flight staged registers (2 sets x GW words)
  float4 slo[2][GW], shi[2][GW];

  auto stage_load = [&](int g, int s) {
#pragma unroll
    for (int i = 0; i < GW; ++i) {
      const float4* er = (const float4*)(emb + chw[g * GW + i] * 64);
      slo[s][i] = er[p];         // c = d0..d0+3
      shi[s][i] = er[p + 8];     // c = d0..d0+3, upper 32 dims
    }
  };

  auto stage_write = [&](int g, int s) {
    const int w0 = g * GW;
#pragma unroll
    for (int i = 0; i < GW; ++i) {
      uint32_t* dst = (uint32_t*)(&xT[(w0 + i) & 7][0]);
      float lv[4] = {slo[s][i].x, slo[s][i].y, slo[s][i].z, slo[s][i].w};
      float hv[4] = {shi[s][i].x, shi[s][i].y, shi[s][i].z, shi[s][i].w};
#pragma unroll
      for (int i2 = 0; i2 < 4; ++i2) {
        uint32_t u = ((uint32_t)__builtin_bit_cast(uint16_t, (__bf16)hv[i2]) << 16)
                   |  (uint32_t)__builtin_bit_cast(uint16_t, (__bf16)lv[i2]);
        dst[(d0 + i2) * 36 + a] = u;   // dword index: row*36 + colpair
      }
    }
  };

  // max over t. t = (reg&3) + 8*(reg>>2) + 4*(lane>>5).
  // upper half (lane>=32): regs 14,15 are t=30,31 -> excluded.
  auto finish = [&](const f32x16& acc, float vbv, int fcol, int w) {
    float m01 = fmaxf(acc[0],  acc[1]);
    float m23 = fmaxf(acc[2],  acc[3]);
    float m45 = fmaxf(acc[4],  acc[5]);
    float m67 = fmaxf(acc[6],  acc[7]);
    float m89 = fmaxf(acc[8],  acc[9]);
    float mab = fmaxf(acc[10], acc[11]);
    float mcd = fmaxf(acc[12], acc[13]);
    float q0 = fmaxf(m01, m23);
    float q1 = fmaxf(m45, m67);
    float q2 = fmaxf(m89, mab);
    float m0 = fmaxf(fmaxf(q0, q1), fmaxf(q2, mcd));
    float m1 = fmaxf(acc[14], acc[15]);
    float mm = (lane < 32) ? fmaxf(m0, m1) : m0;
    float other = __shfl_xor(mm, 32, 64);
    float fullmax = fmaxf(mm, other) + vbv;
    if (lane < 32) out[(bw + w) * 128 + fcol + lane] = fullmax;
  };

  auto compute_word = [&](int w) {
    const __bf16* xb = &xT[w & 7][0] + (lane & 31) * RST + (lane >> 5) * 8;
    f32x16 acc0, acc1;
#pragma unroll
    for (int r = 0; r < 16; ++r) { acc0[r] = 0.0f; acc1[r] = 0.0f; }

    __builtin_amdgcn_s_setprio(1);
#pragma unroll
    for (int kk = 0; kk < 3; ++kk) {
#pragma unroll
      for (int ks = 0; ks < 4; ++ks) {
        // A[m][k] = xT[m+kk][ks*16 + (lane>>5)*8 + j], m = lane&31
        bf16x8 av = *(const bf16x8*)(xb + kk * RST + ks * 16);
        acc0 = __builtin_amdgcn_mfma_f32_32x32x16_bf16(av, bfrag[0][kk * 4 + ks],
                                                       acc0, 0, 0, 0);
        acc1 = __builtin_amdgcn_mfma_f32_32x32x16_bf16(av, bfrag[1][kk * 4 + ks],
                                                       acc1, 0, 0, 0);
      }
    }
    __builtin_amdgcn_s_setprio(0);
    finish(acc0, vb0, np * 64,      w);
    finish(acc1, vb1, np * 64 + 32, w);
  };

  // prologue: groups 0 and 1 in flight, group 0 written to LDS
  stage_load(0, 0);
  stage_write(0, 0);                 // compiler-counted vmcnt for set 0
  stage_load(1, 1);
  asm volatile("s_waitcnt lgkmcnt(0)" ::: "memory");
  __builtin_amdgcn_s_barrier();

#pragma unroll
  for (int g = 0; g < NGRP; ++g) {
    if (g + 2 < NGRP) stage_load(g + 2, g & 1);        // issue early
    if (g + 1 < NGRP) stage_write(g + 1, (g + 1) & 1); // counted vmcnt wait
    asm volatile("s_waitcnt lgkmcnt(0)" ::: "memory");
    __builtin_amdgcn_s_barrier();                      // NO vmcnt drain
    compute_word(g * GW + ws);       // this wave's word of the group
  }
}

extern "C" void kernel_launch(void* const* d_in, const int* in_sizes, int n_in,
                              void* d_out, int out_size, void* d_ws, size_t ws_size,
                              hipStream_t stream) {
  const int*   cid = (const int*)d_in[0];    // [32*512*32] int32
  const float* emb = (const float*)d_in[1];  // [101*64]  f32
  const float* cw  = (const float*)d_in[2];  // [128*64*3] f32
  const float* cb  = (const float*)d_in[3];  // [128] f32
  float* outp = (float*)d_out;               // [16384*128] f32

  hipLaunchKernelGGL(charcnn_mfma, dim3(1024), dim3(256), 0, stream,
                     cid, emb, cb, cw, outp);
}

// Round 4
// 39.813 us; speedup vs baseline: 1.0837x; 1.0837x over previous
//
#include <hip/hip_runtime.h>
#include <cstdint>

// CharEmb: per word (B*S=16384): gather 32 char embeddings (E=64) -> x[64][32]
// (raw view of the [32 chars][64] buffer), conv1d(F=128,K=3,valid,T=30), bias,
// max over t. Output float32 [16384][128].
//
// MFMA formulation (32x32x16 bf16), M=t, N=f (VERIFIED, absmax 0.031):
//   D[t][f] = sum_kk sum_e xT[t+kk][e] * W[f][e][kk]
// - xT[c][e] staged in LDS bf16, row stride 72 elems (144 B, 16B-aligned).
// - conv shift t+kk = pure LDS address offset on the A-fragment read.
// - A frag: A[m=lane&31][k=(lane>>5)*8+j]; B frag: B[k][n=lane&31] (pre-packed).
// - C/D: col=lane&31, row=(reg&3)+8*(reg>>2)+4*(lane>>5); t=30,31 masked.
//
// Round 6: attack the MFMA dependent-chain stall. Rounds 0-3 all ran 1-2
// accumulator chains per wave (same-chain issue distance <= 65 cyc); with
// 32x32 MFMA result latency ~70-130 cyc every k-step stalls, explaining the
// invariant ~1280 cyc/word (3x the 387-cyc MFMA floor) that was insensitive
// to LDS reads, occupancy, and phasing. Now: each wave owns ONE f-tile
// (wv = n-tile, bfrag 48 VGPR, from restored prep_pack_w -- round-3 merge
// regressed and is reverted) and computes FOUR words concurrently: per
// (kk,ks) k-step, 4 independent MFMAs into acc[0..3] -> same-chain distance
// ~130 cyc -> issue-bound. Grid 512 x 32 words: all blocks co-resident
// (2/CU exactly, one round), prologue amortized 2x. T14 staging kept:
// loads for group g+1 issue before compute(g), LDS writes after, counted
// vmcnt; raw s_barrier with lgkmcnt(0) only.

typedef __bf16 bf16x8 __attribute__((ext_vector_type(8)));
typedef float  f32x16 __attribute__((ext_vector_type(16)));

#define GW   4    // words per phase (= independent acc chains per wave)
#define NGRP 8    // phases per block
#define NW   32   // words per block; 512 blocks
#define ROWS 34
#define RST  72   // row stride in bf16 elems (36 dwords)

// Pack conv_w [F=128][E=64][K=3] fp32 -> B-fragment-ordered bf16 in ws:
// pw[(((nt*3+kk)*4+ks)*64 + lane)*8 + j] = w[f=nt*32+(lane&31)][e=ks*16+(lane>>5)*8+j][kk]
__global__ __launch_bounds__(256)
void prep_pack_w(const float* __restrict__ w, __bf16* __restrict__ pw) {
  int i = blockIdx.x * 256 + threadIdx.x;   // 0..24575
  int j    = i & 7;
  int lane = (i >> 3) & 63;
  int ks   = (i >> 9) & 3;
  int t    = i >> 11;        // nt*3 + kk
  int kk   = t % 3;
  int nt   = t / 3;
  int f = nt * 32 + (lane & 31);
  int e = ks * 16 + (lane >> 5) * 8 + j;
  pw[i] = (__bf16)w[f * 192 + e * 3 + kk];
}

__global__ __launch_bounds__(256, 2)
void charcnn_mfma(const int* __restrict__ cid, const float* __restrict__ emb,
                  const float* __restrict__ bias, const __bf16* __restrict__ pw,
                  float* __restrict__ out) {
  // 8 word-buffers (ring), 34 rows x 72 bf16 = 4896 B each = 39168 B.
  __shared__ __align__(16) __bf16 xT[8][ROWS * RST];

  const int tid  = threadIdx.x;
  const int lane = tid & 63;
  const int wv   = tid >> 6;          // wave id == n-tile (f block of 32)

  // persistent B fragments (weights), 12 frags = 48 VGPRs
  bf16x8 bfrag[12];
  const bf16x8* pwv = (const bf16x8*)pw;
#pragma unroll
  for (int q = 0; q < 12; ++q)        // q = kk*4 + ks
    bfrag[q] = pwv[(wv * 12 + q) * 64 + lane];

  const float vb = bias[wv * 32 + (lane & 31)];

  // staging map: thread -> (char slot a, float4 pair p)
  const int a  = tid >> 3;            // 0..31 (char within word)
  const int p  = tid & 7;             // 0..7  (float4 index)
  const int d0 = p * 4;               // row base (c = d0..d0+3)
  const int bw = blockIdx.x * NW;

  // hoist ALL cid loads for this block (longest-latency chain first)
  int chw[NW];
#pragma unroll
  for (int w = 0; w < NW; ++w) chw[w] = cid[(bw + w) * 32 + a];

  // single-set in-flight staging registers (GW words)
  float4 slo[GW], shi[GW];

  auto stage_load = [&](int g) {
#pragma unroll
    for (int i = 0; i < GW; ++i) {
      const float4* er = (const float4*)(emb + chw[g * GW + i] * 64);
      slo[i] = er[p];         // c = d0..d0+3
      shi[i] = er[p + 8];     // c = d0..d0+3, upper 32 dims
    }
  };

  auto stage_write = [&](int g) {
    const int w0 = g * GW;
#pragma unroll
    for (int i = 0; i < GW; ++i) {
      uint32_t* dst = (uint32_t*)(&xT[(w0 + i) & 7][0]);
      float lv[4] = {slo[i].x, slo[i].y, slo[i].z, slo[i].w};
      float hv[4] = {shi[i].x, shi[i].y, shi[i].z, shi[i].w};
#pragma unroll
      for (int i2 = 0; i2 < 4; ++i2) {
        uint32_t u = ((uint32_t)__builtin_bit_cast(uint16_t, (__bf16)hv[i2]) << 16)
                   |  (uint32_t)__builtin_bit_cast(uint16_t, (__bf16)lv[i2]);
        dst[(d0 + i2) * 36 + a] = u;   // dword index: row*36 + colpair
      }
    }
  };

  // max over t. t = (reg&3) + 8*(reg>>2) + 4*(lane>>5).
  // upper half (lane>=32): regs 14,15 are t=30,31 -> excluded.
  auto finish = [&](const f32x16& acc, int w) {
    float m01 = fmaxf(acc[0],  acc[1]);
    float m23 = fmaxf(acc[2],  acc[3]);
    float m45 = fmaxf(acc[4],  acc[5]);
    float m67 = fmaxf(acc[6],  acc[7]);
    float m89 = fmaxf(acc[8],  acc[9]);
    float mab = fmaxf(acc[10], acc[11]);
    float mcd = fmaxf(acc[12], acc[13]);
    float q0 = fmaxf(m01, m23);
    float q1 = fmaxf(m45, m67);
    float q2 = fmaxf(m89, mab);
    float m0 = fmaxf(fmaxf(q0, q1), fmaxf(q2, mcd));
    float m1 = fmaxf(acc[14], acc[15]);
    float mm = (lane < 32) ? fmaxf(m0, m1) : m0;
    float other = __shfl_xor(mm, 32, 64);
    float fullmax = fmaxf(mm, other) + vb;
    if (lane < 32) out[(bw + w) * 128 + wv * 32 + lane] = fullmax;
  };

  // compute the GW=4 words of group g as 4 INDEPENDENT acc chains:
  // per (kk,ks) k-step, 4 MFMAs into different accs -> same-chain issue
  // distance ~4x32 cyc, covers MFMA result latency.
  auto compute_group = [&](int g) {
    const int w0 = g * GW;
    const __bf16* xb0 = &xT[(w0 + 0) & 7][0] + (lane & 31) * RST + (lane >> 5) * 8;
    const __bf16* xb1 = &xT[(w0 + 1) & 7][0] + (lane & 31) * RST + (lane >> 5) * 8;
    const __bf16* xb2 = &xT[(w0 + 2) & 7][0] + (lane & 31) * RST + (lane >> 5) * 8;
    const __bf16* xb3 = &xT[(w0 + 3) & 7][0] + (lane & 31) * RST + (lane >> 5) * 8;
    f32x16 acc0, acc1, acc2, acc3;
#pragma unroll
    for (int r = 0; r < 16; ++r) {
      acc0[r] = 0.0f; acc1[r] = 0.0f; acc2[r] = 0.0f; acc3[r] = 0.0f;
    }

    __builtin_amdgcn_s_setprio(1);
#pragma unroll
    for (int kk = 0; kk < 3; ++kk) {
#pragma unroll
      for (int ks = 0; ks < 4; ++ks) {
        const int off = kk * RST + ks * 16;
        bf16x8 bq = bfrag[kk * 4 + ks];
        bf16x8 a0 = *(const bf16x8*)(xb0 + off);
        bf16x8 a1 = *(const bf16x8*)(xb1 + off);
        bf16x8 a2 = *(const bf16x8*)(xb2 + off);
        bf16x8 a3 = *(const bf16x8*)(xb3 + off);
        acc0 = __builtin_amdgcn_mfma_f32_32x32x16_bf16(a0, bq, acc0, 0, 0, 0);
        acc1 = __builtin_amdgcn_mfma_f32_32x32x16_bf16(a1, bq, acc1, 0, 0, 0);
        acc2 = __builtin_amdgcn_mfma_f32_32x32x16_bf16(a2, bq, acc2, 0, 0, 0);
        acc3 = __builtin_amdgcn_mfma_f32_32x32x16_bf16(a3, bq, acc3, 0, 0, 0);
      }
    }
    __builtin_amdgcn_s_setprio(0);
    finish(acc0, w0 + 0);
    finish(acc1, w0 + 1);
    finish(acc2, w0 + 2);
    finish(acc3, w0 + 3);
  };

  // prologue: group 0 staged and visible
  stage_load(0);
  stage_write(0);
  asm volatile("s_waitcnt lgkmcnt(0)" ::: "memory");
  __builtin_amdgcn_s_barrier();

  for (int g = 0; g < NGRP; ++g) {
    if (g + 1 < NGRP) stage_load(g + 1);    // issue early (T14)
    compute_group(g);                       // ~1550 cyc MFMA hides the loads
    if (g + 1 < NGRP) stage_write(g + 1);   // counted vmcnt, then LDS writes
    asm volatile("s_waitcnt lgkmcnt(0)" ::: "memory");
    __builtin_amdgcn_s_barrier();           // no vmcnt drain
  }
}

extern "C" void kernel_launch(void* const* d_in, const int* in_sizes, int n_in,
                              void* d_out, int out_size, void* d_ws, size_t ws_size,
                              hipStream_t stream) {
  const int*   cid = (const int*)d_in[0];    // [32*512*32] int32
  const float* emb = (const float*)d_in[1];  // [101*64]  f32
  const float* cw  = (const float*)d_in[2];  // [128*64*3] f32
  const float* cb  = (const float*)d_in[3];  // [128] f32
  float* outp = (float*)d_out;               // [16384*128] f32
  __bf16* pw = (__bf16*)d_ws;                // 24576 bf16 = 48 KB

  hipLaunchKernelGGL(prep_pack_w, dim3(96), dim3(256), 0, stream, cw, pw);
  hipLaunchKernelGGL(charcnn_mfma, dim3(512), dim3(256), 0, stream,
                     cid, emb, cb, (const __bf16*)pw, outp);
}

// Round 5
// 34.961 us; speedup vs baseline: 1.2341x; 1.1388x over previous
//
#include <hip/hip_runtime.h>
#include <cstdint>

// CharEmb: per word (B*S=16384): gather 32 char embeddings (E=64) -> x[64][32]
// (raw view of the [32 chars][64] buffer), conv1d(F=128,K=3,valid,T=30), bias,
// max over t. Output float32 [16384][128].
//
// MFMA formulation (32x32x16 bf16), M=t, N=f (VERIFIED, absmax 0.031):
//   D[t][f] = sum_kk sum_e xT[t+kk][e] * W[f][e][kk]
// - xT[c][e] in LDS bf16, row stride 72 elems (144 B); xT[r][2a+s] =
//   emb[ch[a]][r+32s]  (raw-view transpose; r=0..31 real, 32/33 garbage ->
//   feed ONLY masked t=30,31 = upper-half acc regs 14,15, excluded in finish).
// - A frag: A[m=lane&31][k=(lane>>5)*8+j]; B frag: B[k][n=lane&31] (pre-packed).
// - C/D: col=lane&31, row=(reg&3)+8*(reg>>2)+4*(lane>>5).
//
// Round 7: WAVE-AUTONOMOUS, BARRIER-FREE. R0-R4 evidence: no pipe >35% busy
// (R3 profile: Mfma 21%, VALU 15%, LDS ~35% by model) and the kernel is
// insensitive to LDS traffic, occupancy, and phasing -> dependency-bound via
// block-wide barrier lockstep. Enabler: the LDS dword at [r][pair a] is
// pack(bf16(emb[c][r]), bf16(emb[c][r+32])) = Dt[c][r], precomputed (12.9 KB,
// L1-resident). Staging = pure copy (4 dwordx4 + 16 free-2-way ds_write_b32
// per lane), so each wave stages its OWN double-buffer: ZERO s_barrier in the
// whole kernel; same-wave lgkmcnt gives all ordering. Each wave: 2 f-tiles
// (np=wv&1, 2 indep MFMA chains), words ws+2j (ws=wv>>1), T14 ping-pong
// (load j+1 early, write j+1 after compute j). Grid 1024 (stagger), 2 blk/CU.

typedef __bf16 bf16x8 __attribute__((ext_vector_type(8)));
typedef float  f32x16 __attribute__((ext_vector_type(16)));

#define NW   16   // words per block; 1024 blocks
#define WPW  8    // words per wave (= NW/2, split by ws parity)
#define ROWS 34
#define RST  72   // row stride in bf16 elems (36 dwords)

// prep: pw pack (B-fragment order, as verified) + Dt pack.
// pw[(((nt*3+kk)*4+ks)*64+lane)*8+j] = w[nt*32+(lane&31)][ks*16+(lane>>5)*8+j][kk]
// Dt[c*32+r] = (bf16(emb[c][32+r])<<16) | bf16(emb[c][r])
__global__ __launch_bounds__(256)
void prep_pack(const float* __restrict__ w, const float* __restrict__ emb,
               __bf16* __restrict__ pw, uint32_t* __restrict__ Dt) {
  int i = blockIdx.x * 256 + threadIdx.x;
  if (i < 24576) {
    int j    = i & 7;
    int lane = (i >> 3) & 63;
    int ks   = (i >> 9) & 3;
    int t    = i >> 11;        // nt*3 + kk
    int kk   = t % 3;
    int nt   = t / 3;
    int f = nt * 32 + (lane & 31);
    int e = ks * 16 + (lane >> 5) * 8 + j;
    pw[i] = (__bf16)w[f * 192 + e * 3 + kk];
  } else if (i < 24576 + 3232) {
    int i2 = i - 24576;
    int c = i2 >> 5, r = i2 & 31;
    uint32_t lo = (uint32_t)__builtin_bit_cast(uint16_t, (__bf16)emb[c * 64 + r]);
    uint32_t hi = (uint32_t)__builtin_bit_cast(uint16_t, (__bf16)emb[c * 64 + 32 + r]);
    Dt[i2] = (hi << 16) | lo;
  }
}

__global__ __launch_bounds__(256, 2)
void charcnn_mfma(const int* __restrict__ cid, const uint32_t* __restrict__ Dt,
                  const float* __restrict__ bias, const __bf16* __restrict__ pw,
                  float* __restrict__ out) {
  // per-wave private double buffers: 4 waves x 2 x 4896 B = 39168 B
  __shared__ __align__(16) __bf16 xT[4][2][ROWS * RST];

  const int tid  = threadIdx.x;
  const int lane = tid & 63;
  const int wv   = tid >> 6;
  const int np   = wv & 1;    // f-tile pair: f in [np*64, np*64+64)
  const int ws   = wv >> 1;   // word parity this wave owns

  // persistent B fragments for TWO f-tiles: 24 frags = 96 VGPRs
  bf16x8 bfrag[2][12];
  const bf16x8* pwv = (const bf16x8*)pw;
#pragma unroll
  for (int nt = 0; nt < 2; ++nt)
#pragma unroll
    for (int q = 0; q < 12; ++q)        // q = kk*4 + ks
      bfrag[nt][q] = pwv[((np * 2 + nt) * 12 + q) * 64 + lane];

  const float vb0 = bias[(np * 2 + 0) * 32 + (lane & 31)];
  const float vb1 = bias[(np * 2 + 1) * 32 + (lane & 31)];

  const int bw = blockIdx.x * NW;

  // hoist this wave's cid vectors: c0[j] = cid[(bw+ws+2j)*32 + (lane&31)]
  int c0[WPW];
#pragma unroll
  for (int j = 0; j < WPW; ++j)
    c0[j] = cid[(bw + ws + 2 * j) * 32 + (lane & 31)];

  // staging role: lane -> (char a = lane>>1, half s = lane&1: dwords 16s..16s+15)
  const int sa = lane >> 1;
  const int ss = lane & 1;

  uint4 sd[4];   // in-flight Dt data (64 B/lane)

  auto stage_load = [&](int j) {
    int ch = __shfl(c0[j], lane >> 1);             // char for slot sa
    const uint4* row = (const uint4*)(Dt + ch * 32) + ss * 4;
#pragma unroll
    for (int q = 0; q < 4; ++q) sd[q] = row[q];
  };

  auto stage_write = [&](__bf16* buf) {
    uint32_t* d = (uint32_t*)buf + sa;
#pragma unroll
    for (int q = 0; q < 4; ++q) {
      d[(16 * ss + q * 4 + 0) * 36] = sd[q].x;     // banks: (4k+a) mod 32,
      d[(16 * ss + q * 4 + 1) * 36] = sd[q].y;     // 2 lanes/bank = free
      d[(16 * ss + q * 4 + 2) * 36] = sd[q].z;
      d[(16 * ss + q * 4 + 3) * 36] = sd[q].w;
    }
  };

  // max over t. t = (reg&3) + 8*(reg>>2) + 4*(lane>>5).
  // upper half (lane>=32): regs 14,15 are t=30,31 -> excluded (garbage rows).
  auto finish = [&](const f32x16& acc, float vbv, int fcol, int w) {
    float m01 = fmaxf(acc[0],  acc[1]);
    float m23 = fmaxf(acc[2],  acc[3]);
    float m45 = fmaxf(acc[4],  acc[5]);
    float m67 = fmaxf(acc[6],  acc[7]);
    float m89 = fmaxf(acc[8],  acc[9]);
    float mab = fmaxf(acc[10], acc[11]);
    float mcd = fmaxf(acc[12], acc[13]);
    float q0 = fmaxf(m01, m23);
    float q1 = fmaxf(m45, m67);
    float q2 = fmaxf(m89, mab);
    float m0 = fmaxf(fmaxf(q0, q1), fmaxf(q2, mcd));
    float m1 = fmaxf(acc[14], acc[15]);
    float mm = (lane < 32) ? fmaxf(m0, m1) : m0;
    float other = __shfl_xor(mm, 32, 64);
    float fullmax = fmaxf(mm, other) + vbv;
    if (lane < 32) out[(bw + w) * 128 + fcol + lane] = fullmax;
  };

  auto compute_word = [&](int w, const __bf16* buf) {
    const __bf16* xb = buf + (lane & 31) * RST + (lane >> 5) * 8;
    f32x16 acc0, acc1;
#pragma unroll
    for (int r = 0; r < 16; ++r) { acc0[r] = 0.0f; acc1[r] = 0.0f; }

#pragma unroll
    for (int kk = 0; kk < 3; ++kk) {
#pragma unroll
      for (int ks = 0; ks < 4; ++ks) {
        bf16x8 av = *(const bf16x8*)(xb + kk * RST + ks * 16);
        acc0 = __builtin_amdgcn_mfma_f32_32x32x16_bf16(av, bfrag[0][kk * 4 + ks],
                                                       acc0, 0, 0, 0);
        acc1 = __builtin_amdgcn_mfma_f32_32x32x16_bf16(av, bfrag[1][kk * 4 + ks],
                                                       acc1, 0, 0, 0);
      }
    }
    finish(acc0, vb0, np * 64,      w);
    finish(acc1, vb1, np * 64 + 32, w);
  };

  // prologue: word 0 staged into buf 0 (same-wave lgkmcnt orders write->read)
  stage_load(0);
  stage_write(&xT[wv][0][0]);

  // T14 ping-pong, NO barriers anywhere
#pragma unroll
  for (int j = 0; j < WPW; ++j) {
    if (j + 1 < WPW) stage_load(j + 1);            // issue Dt loads early
    compute_word(ws + 2 * j, &xT[wv][j & 1][0]);   // reads wait on lgkmcnt only
    if (j + 1 < WPW) stage_write(&xT[wv][(j + 1) & 1][0]);  // counted vmcnt
  }
}

extern "C" void kernel_launch(void* const* d_in, const int* in_sizes, int n_in,
                              void* d_out, int out_size, void* d_ws, size_t ws_size,
                              hipStream_t stream) {
  const int*   cid = (const int*)d_in[0];    // [32*512*32] int32
  const float* emb = (const float*)d_in[1];  // [101*64]  f32
  const float* cw  = (const float*)d_in[2];  // [128*64*3] f32
  const float* cb  = (const float*)d_in[3];  // [128] f32
  float* outp = (float*)d_out;               // [16384*128] f32
  __bf16*   pw = (__bf16*)d_ws;              // 24576 bf16 = 48 KB
  uint32_t* Dt = (uint32_t*)((char*)d_ws + 49152);  // 3232 dwords = 12.9 KB

  hipLaunchKernelGGL(prep_pack, dim3(109), dim3(256), 0, stream, cw, emb, pw, Dt);
  hipLaunchKernelGGL(charcnn_mfma, dim3(1024), dim3(256), 0, stream,
                     cid, Dt, cb, pw, outp);
}